// Round 8
// baseline (863.595 us; speedup 1.0000x reference)
//
#include <hip/hip_runtime.h>

typedef __bf16 bf16;
typedef _Float16 f16;
typedef __bf16 bf16x8 __attribute__((ext_vector_type(8)));
typedef _Float16 f16x8 __attribute__((ext_vector_type(8)));
typedef _Float16 f16x4 __attribute__((ext_vector_type(4)));
typedef float f32x4 __attribute__((ext_vector_type(4)));

#define NROWS 4096
#define DIN 1024
#define DA 512

template <typename T> struct V8;
template <> struct V8<f16> { using type = f16x8; };
template <> struct V8<bf16> { using type = bf16x8; };

__device__ __forceinline__ f32x4 mfma16(f16x8 a, f16x8 b, f32x4 c) {
  return __builtin_amdgcn_mfma_f32_16x16x32_f16(a, b, c, 0, 0, 0);
}
__device__ __forceinline__ f32x4 mfma16(bf16x8 a, bf16x8 b, f32x4 c) {
  return __builtin_amdgcn_mfma_f32_16x16x32_bf16(a, b, c, 0, 0, 0);
}

__device__ __forceinline__ void gload_lds16(const void* g, void* l) {
  __builtin_amdgcn_global_load_lds((const __attribute__((address_space(1))) void*)g,
                                   (__attribute__((address_space(3))) void*)l, 16, 0, 0);
}

// ---------------- prep kernels ----------------

__global__ void cast_kernel(const float* __restrict__ s1, const float* __restrict__ s2,
                            f16* __restrict__ d1, f16* __restrict__ d2, int n) {
  const float* s = blockIdx.z ? s2 : s1;
  f16* d = blockIdx.z ? d2 : d1;
  int i = (blockIdx.x * blockDim.x + threadIdx.x) * 4;
  if (i < n) {
    float4 v = *(const float4*)(s + i);
    f16x4 o;
    o[0] = (f16)v.x; o[1] = (f16)v.y; o[2] = (f16)v.z; o[3] = (f16)v.w;
    *(f16x4*)(d + i) = o;
  }
}

// dst[c][r] = (f16) src[r][c]
__global__ void transpose_f32(const float* __restrict__ w0, const float* __restrict__ w1,
                              const float* __restrict__ w2, f16* __restrict__ dst,
                              size_t dstride, int rows, int cols) {
  const float* s = blockIdx.z == 0 ? w0 : (blockIdx.z == 1 ? w1 : w2);
  f16* d = dst + (size_t)blockIdx.z * dstride;
  __shared__ float tile[32][33];
  int bc = blockIdx.x * 32, br = blockIdx.y * 32;
  int tx = threadIdx.x, ty = threadIdx.y;
  for (int i = ty; i < 32; i += 8)
    tile[i][tx] = s[(size_t)(br + i) * cols + bc + tx];
  __syncthreads();
  for (int i = ty; i < 32; i += 8)
    d[(size_t)(bc + i) * rows + br + tx] = (f16)tile[tx][i];
}

// bf16 [rows,cols] -> bf16 [cols][rows]
__global__ void transpose_b16(const bf16* __restrict__ src, size_t sstride,
                              bf16* __restrict__ dst, size_t dstride, int rows, int cols) {
  const bf16* s = src + (size_t)blockIdx.z * sstride;
  bf16* d = dst + (size_t)blockIdx.z * dstride;
  __shared__ float tile[32][33];
  int bc = blockIdx.x * 32, br = blockIdx.y * 32;
  int tx = threadIdx.x, ty = threadIdx.y;
  for (int i = ty; i < 32; i += 8)
    tile[i][tx] = (float)s[(size_t)(br + i) * cols + bc + tx];
  __syncthreads();
  for (int i = ty; i < 32; i += 8)
    d[(size_t)(bc + i) * rows + br + tx] = (bf16)tile[tx][i];
}

// merge split-K PV partials: mid = (pO[z]+pO[2+z]) / (rs[z]+rs[2+z]), f16
__global__ void merge_kernel(const float* __restrict__ pO, const float* __restrict__ prs,
                             f16* __restrict__ mid) {
  const size_t QS = (size_t)NROWS * DA;
  size_t e = ((size_t)blockIdx.x * blockDim.x + threadIdx.x) * 4;
  int z = (int)(e / QS);
  size_t rem = e - (size_t)z * QS;
  int row = (int)(rem / DA);
  float4 a = *(const float4*)(pO + (size_t)z * QS + rem);
  float4 b = *(const float4*)(pO + (size_t)(2 + z) * QS + rem);
  float rs = prs[z * NROWS + row] + prs[(2 + z) * NROWS + row];
  float inv = 1.0f / rs;
  f16x4 o;
  o[0] = (f16)((a.x + b.x) * inv);
  o[1] = (f16)((a.y + b.y) * inv);
  o[2] = (f16)((a.z + b.z) * inv);
  o[3] = (f16)((a.w + b.w) * inv);
  *(f16x4*)(mid + (size_t)z * QS + rem) = o;
}

// ---------------- 8-phase 256-row GEMM template ----------------
// C[256 x BN tile] = A[M,K] @ Bt[N,K]^T over K window [k0, k0+NT*64).
// 8 waves (2M x 4N), BK=64, M-interleaved wave frags (phase p consumes global
// A-rows p*64..p*64+63). Double-buffered LDS, 1-tile-ahead staging, counted
// vmcnt; XOR swizzle chunk^=(row&7) with inverse-swizzled global source.
// BN=256: stage halves per tile [B0,B1,A0,A1]; BN=128: [B0,A0,A1].
// EPI 0: +bias, store f16/bf16 per storebf[z]
// EPI 1: exp(), store bf16
// EPI 2: split-K partial: f32 acc to C + partial rowsum (ones-MFMA) to rsO

template <typename TIN>
struct G8Args {
  const TIN* A[6];
  const TIN* B[6];
  const float* bias[6];
  void* C[6];
  float* rsO[6];
  int k0[6];
  int storebf[6];
  int lda, ldb, ldc;
};

template <typename TIN, int EPI, int BN, int NT>
__global__ __launch_bounds__(512, 1) void g8(G8Args<TIN> args) {
  using vec8 = typename V8<TIN>::type;
  constexpr int NFR = BN / 64;           // 4 or 2 n-frags per wave
  constexpr int BBUF = BN * 128;         // B bytes per buffer
  constexpr int BUFSZ = 32768 + BBUF;
  __shared__ __align__(16) char smem[2 * BUFSZ];

  const int z = blockIdx.z;
  const TIN* __restrict__ A = args.A[z];
  const TIN* __restrict__ B = args.B[z];
  const int lda = args.lda, ldb = args.ldb;
  const int k0 = args.k0[z];

  // T1 XCD-aware bijective swizzle (all grids here are %8==0 per z)
  int blkM, blkN;
  {
    const int gx = gridDim.x;
    const int nwg = gx * gridDim.y;
    const int lin = blockIdx.y * gx + blockIdx.x;
    const int q = nwg >> 3;
    const int nl = (lin & 7) * q + (lin >> 3);
    blkN = nl % gx;
    blkM = nl / gx;
  }

  const int tid = threadIdx.x;
  const int w = tid >> 6, lane = tid & 63;
  const int wm = w & 1, wn = w >> 1;     // 2M x 4N
  const int lr = lane & 15, lh = lane >> 4;

  const TIN* Abase = A + (size_t)blkM * 256 * lda;
  const TIN* Bbase = B + (size_t)blkN * BN * ldb;

  f32x4 acc[8][NFR] = {};
  f32x4 rs[8] = {};
  vec8 ones;
  if constexpr (EPI == 2) {
#pragma unroll
    for (int i = 0; i < 8; ++i) ones[i] = (TIN)1.0f;
  }
  vec8 af[2][2], bfr[NFR][2];

#define STAGE_A(buf, hf, kt)                                                    \
  {                                                                             \
    char* dst_ = smem + (buf)*BUFSZ + (hf)*16384;                               \
    const TIN* src_ = Abase + (size_t)((hf)*128) * lda + (kt);                  \
    _Pragma("unroll")                                                           \
    for (int i_ = 0; i_ < 2; ++i_) {                                            \
      int c_ = i_ * 512 + tid;                                                  \
      int r_ = c_ >> 3, q_ = c_ & 7;                                            \
      gload_lds16(src_ + (size_t)r_ * lda + ((q_ ^ (r_ & 7)) << 3),             \
                  dst_ + c_ * 16);                                              \
    }                                                                           \
  }
#define STAGE_B(buf, hf, kt)                                                    \
  {                                                                             \
    char* dst_ = smem + (buf)*BUFSZ + 32768 + (hf)*16384;                       \
    const TIN* src_ = Bbase + (size_t)((hf)*128) * ldb + (kt);                  \
    _Pragma("unroll")                                                           \
    for (int i_ = 0; i_ < 2; ++i_) {                                            \
      int c_ = i_ * 512 + tid;                                                  \
      int r_ = c_ >> 3, q_ = c_ & 7;                                            \
      gload_lds16(src_ + (size_t)r_ * ldb + ((q_ ^ (r_ & 7)) << 3),             \
                  dst_ + c_ * 16);                                              \
    }                                                                           \
  }
#define LDA_PHASE(buf, p)                                                       \
  {                                                                             \
    char* Ab_ = smem + (buf)*BUFSZ;                                             \
    _Pragma("unroll")                                                           \
    for (int fi_ = 0; fi_ < 2; ++fi_) {                                         \
      int row_ = (((p)*2 + fi_) * 2 + wm) * 16 + lr;                            \
      _Pragma("unroll")                                                         \
      for (int kk_ = 0; kk_ < 2; ++kk_) {                                       \
        int cc_ = (kk_ * 4 + lh) ^ (row_ & 7);                                  \
        af[fi_][kk_] = *(const vec8*)(Ab_ + row_ * 128 + cc_ * 16);             \
      }                                                                         \
    }                                                                           \
  }
#define LDB_ALL(buf)                                                            \
  {                                                                             \
    char* Bb_ = smem + (buf)*BUFSZ + 32768;                                     \
    _Pragma("unroll")                                                           \
    for (int n_ = 0; n_ < NFR; ++n_) {                                          \
      int row_ = wn * (BN / 4) + n_ * 16 + lr;                                  \
      _Pragma("unroll")                                                         \
      for (int kk_ = 0; kk_ < 2; ++kk_) {                                       \
        int cc_ = (kk_ * 4 + lh) ^ (row_ & 7);                                  \
        bfr[n_][kk_] = *(const vec8*)(Bb_ + row_ * 128 + cc_ * 16);             \
      }                                                                         \
    }                                                                           \
  }
#define MFMA_PHASE(p)                                                           \
  {                                                                             \
    _Pragma("unroll")                                                           \
    for (int fi_ = 0; fi_ < 2; ++fi_) {                                         \
      _Pragma("unroll")                                                         \
      for (int n_ = 0; n_ < NFR; ++n_) {                                        \
        _Pragma("unroll")                                                       \
        for (int kk_ = 0; kk_ < 2; ++kk_)                                       \
          acc[(p)*2 + fi_][n_] = mfma16(af[fi_][kk_], bfr[n_][kk_],             \
                                        acc[(p)*2 + fi_][n_]);                  \
      }                                                                         \
      if constexpr (EPI == 2) {                                                 \
        if (wn == 0) {                                                          \
          _Pragma("unroll")                                                     \
          for (int kk_ = 0; kk_ < 2; ++kk_)                                     \
            rs[(p)*2 + fi_] = mfma16(af[fi_][kk_], ones, rs[(p)*2 + fi_]);      \
        }                                                                       \
      }                                                                         \
    }                                                                           \
  }
#define BAR() __builtin_amdgcn_s_barrier()
#define LGK0()                                          \
  asm volatile("s_waitcnt lgkmcnt(0)" ::: "memory");    \
  __builtin_amdgcn_sched_barrier(0)

  // prologue
  if constexpr (NFR == 4) {
    STAGE_B(0, 0, k0); STAGE_B(0, 1, k0); STAGE_A(0, 0, k0); STAGE_A(0, 1, k0);
  } else {
    STAGE_B(0, 0, k0); STAGE_A(0, 0, k0); STAGE_A(0, 1, k0);
  }
  asm volatile("s_waitcnt vmcnt(2)" ::: "memory");  // last A-half still in flight
  BAR();

  for (int t = 0; t < NT; ++t) {
    const int cur = t & 1, nxt = cur ^ 1;
    const int ktn = k0 + (t + 1) * 64;
    const bool st = (t < NT - 1);
    // ---- ph0: uses B + A-half0 ----
    if (st) { STAGE_B(nxt, 0, ktn); }
    LDB_ALL(cur);
    LDA_PHASE(cur, 0);
    BAR(); LGK0();
    __builtin_amdgcn_s_setprio(1); MFMA_PHASE(0); __builtin_amdgcn_s_setprio(0);
    BAR();
    // ---- ph1: uses A-half0 ----
    if (st) {
      if constexpr (NFR == 4) { STAGE_B(nxt, 1, ktn); } else { STAGE_A(nxt, 0, ktn); }
    }
    LDA_PHASE(cur, 1);
    BAR(); LGK0();
    __builtin_amdgcn_s_setprio(1); MFMA_PHASE(1); __builtin_amdgcn_s_setprio(0);
    if (st) { asm volatile("s_waitcnt vmcnt(4)" ::: "memory"); }  // A-half1(t) landed
    else    { asm volatile("s_waitcnt vmcnt(0)" ::: "memory"); }
    BAR();
    // ---- ph2: uses A-half1 ----
    if (st) {
      if constexpr (NFR == 4) { STAGE_A(nxt, 0, ktn); } else { STAGE_A(nxt, 1, ktn); }
    }
    LDA_PHASE(cur, 2);
    BAR(); LGK0();
    __builtin_amdgcn_s_setprio(1); MFMA_PHASE(2); __builtin_amdgcn_s_setprio(0);
    BAR();
    // ---- ph3: uses A-half1 ----
    if (st) {
      if constexpr (NFR == 4) { STAGE_A(nxt, 1, ktn); }
    }
    LDA_PHASE(cur, 3);
    BAR(); LGK0();
    __builtin_amdgcn_s_setprio(1); MFMA_PHASE(3); __builtin_amdgcn_s_setprio(0);
    if (st) { asm volatile("s_waitcnt vmcnt(2)" ::: "memory"); }  // next B+A0 landed
    BAR();
  }

  // ---- epilogue ----
  const int row0 = blkM * 256;
  const int col0 = blkN * BN + wn * (BN / 4);
  const int ldc = args.ldc;
#pragma unroll
  for (int a = 0; a < 8; ++a) {
#pragma unroll
    for (int n = 0; n < NFR; ++n) {
#pragma unroll
      for (int rr = 0; rr < 4; ++rr) {
        int row = row0 + (a * 2 + wm) * 16 + lh * 4 + rr;
        int col = col0 + n * 16 + lr;
        float v = acc[a][n][rr];
        if constexpr (EPI == 0) {
          float b = v + args.bias[z][col];
          if (args.storebf[z])
            ((bf16*)args.C[z])[(size_t)row * ldc + col] = (bf16)b;
          else
            ((f16*)args.C[z])[(size_t)row * ldc + col] = (f16)b;
        } else if constexpr (EPI == 1) {
          ((bf16*)args.C[z])[(size_t)row * ldc + col] = (bf16)__expf(v);
        } else {
          ((float*)args.C[z])[(size_t)row * ldc + col] = v;
        }
      }
    }
  }
  if constexpr (EPI == 2) {
    if (wn == 0 && lr == 0) {
      float* rsO = args.rsO[z];
#pragma unroll
      for (int a = 0; a < 8; ++a)
#pragma unroll
        for (int rr = 0; rr < 4; ++rr)
          rsO[row0 + (a * 2 + wm) * 16 + lh * 4 + rr] = rs[a][rr];
    }
  }
#undef STAGE_A
#undef STAGE_B
#undef LDA_PHASE
#undef LDB_ALL
#undef MFMA_PHASE
#undef BAR
#undef LGK0
}

// ---------------- out GEMM (128x128, 2-phase) ----------------
// out[z] = mid[z] @ WoT^T + bo (f32)

__global__ __launch_bounds__(512) void out_gemm(const f16* __restrict__ mid,
                                                const f16* __restrict__ woT,
                                                const float* __restrict__ bo,
                                                float* __restrict__ out) {
  __shared__ __align__(16) f16 As[128 * 64];
  __shared__ __align__(16) f16 Bs[128 * 64];

  const int z = blockIdx.z;
  const f16* __restrict__ Ag = mid + (size_t)z * NROWS * DA;
  float* __restrict__ Cg = out + (size_t)z * NROWS * DIN;

  int blkM, blkN;
  {
    const int gx = gridDim.x;
    const int nwg = gx * gridDim.y;
    const int lin = blockIdx.y * gx + blockIdx.x;
    const int q = nwg >> 3;
    const int nl = (lin & 7) * q + (lin >> 3);
    blkN = nl % gx;
    blkM = nl / gx;
  }

  const int tid = threadIdx.x;
  const int w = tid >> 6, lane = tid & 63;
  const int wr = w >> 2, wc = w & 3;
  const int lrow = lane & 15, lhi = lane >> 4;

  const f16* Abase = Ag + (size_t)blkM * 128 * DA;
  const f16* Bbase = woT + (size_t)blkN * 128 * DA;

  f32x4 acc[4][2] = {};

  for (int kt = 0; kt < DA; kt += 64) {
#pragma unroll
    for (int it = 0; it < 2; ++it) {
      int cidx = (it * 8 + w) * 64 + lane;
      int row = cidx >> 3;
      int col = (cidx & 7) << 3;
      gload_lds16(Abase + (size_t)row * DA + kt + col, (char*)As + (size_t)cidx * 16);
    }
#pragma unroll
    for (int it = 0; it < 2; ++it) {
      int cidx = (it * 8 + w) * 64 + lane;
      int row = cidx >> 3;
      int col = (cidx & 7) << 3;
      gload_lds16(Bbase + (size_t)row * DA + kt + col, (char*)Bs + (size_t)cidx * 16);
    }
    __syncthreads();

    f16x8 af[4][2], bfr[2][2];
#pragma unroll
    for (int m = 0; m < 4; ++m)
#pragma unroll
      for (int kk = 0; kk < 2; ++kk)
        af[m][kk] = *(const f16x8*)&As[(wr * 64 + m * 16 + lrow) * 64 + kk * 32 + lhi * 8];
#pragma unroll
    for (int n = 0; n < 2; ++n)
#pragma unroll
      for (int kk = 0; kk < 2; ++kk)
        bfr[n][kk] = *(const f16x8*)&Bs[(wc * 32 + n * 16 + lrow) * 64 + kk * 32 + lhi * 8];

#pragma unroll
    for (int m = 0; m < 4; ++m)
#pragma unroll
      for (int n = 0; n < 2; ++n)
#pragma unroll
        for (int kk = 0; kk < 2; ++kk)
          acc[m][n] = mfma16(af[m][kk], bfr[n][kk], acc[m][n]);
    __syncthreads();
  }

  const int row0 = blkM * 128 + wr * 64;
  const int col0 = blkN * 128 + wc * 32;
#pragma unroll
  for (int m = 0; m < 4; ++m)
#pragma unroll
    for (int n = 0; n < 2; ++n)
#pragma unroll
      for (int r = 0; r < 4; ++r) {
        int row = row0 + m * 16 + lhi * 4 + r;
        int col = col0 + n * 16 + lrow;
        Cg[(size_t)row * DIN + col] = acc[m][n][r] + bo[col];
      }
}

// ---------------- launch ----------------

extern "C" void kernel_launch(void* const* d_in, const int* in_sizes, int n_in,
                              void* d_out, int out_size, void* d_ws, size_t ws_size,
                              hipStream_t stream) {
  const float* in1 = (const float*)d_in[0];
  const float* in2 = (const float*)d_in[1];
  const float* Wq = (const float*)d_in[2];
  const float* bq = (const float*)d_in[3];
  const float* Wk = (const float*)d_in[4];
  const float* bk = (const float*)d_in[5];
  const float* Wv = (const float*)d_in[6];
  const float* bv = (const float*)d_in[7];
  const float* Wo = (const float*)d_in[8];
  const float* bo = (const float*)d_in[9];
  float* out = (float*)d_out;

  const size_t IN_E = (size_t)NROWS * DIN;   // 4M
  const size_t WT_E = (size_t)DA * DIN;      // 512K
  const size_t QS = (size_t)NROWS * DA;      // 2M
  const size_t PS = (size_t)NROWS * NROWS;   // 16M

  f16* qk = (f16*)d_ws;                      // 16 MB (dead after QK)
  f16* in_hf = qk + 4 * QS;                  // 16 MB (dead after proj)
  bf16* vv = (bf16*)(in_hf + 2 * IN_E);      // 8 MB (dead after transpose)
  f16* wt = (f16*)(vv + 2 * QS);             // 3 MB
  f16* woT = wt + 3 * WT_E;                  // 1 MB
  bf16* vt = (bf16*)(woT + WT_E);            // 8 MB
  bf16* P = vt + 2 * QS;                     // 64 MB
  f16* mid = (f16*)(P + 2 * PS);             // 8 MB
  float* pO = (float*)d_ws;                  // 32 MB, aliases qk+in_hf
  float* prs = (float*)vv;                   // 64 KB, aliases vv

  // 1. cast inputs to fp16
  cast_kernel<<<dim3((unsigned)(IN_E / 1024), 1, 2), dim3(256), 0, stream>>>(
      in1, in2, in_hf, in_hf + IN_E, (int)IN_E);

  // 2. transpose-cast weights
  transpose_f32<<<dim3(DA / 32, DIN / 32, 3), dim3(32, 8), 0, stream>>>(
      Wq, Wk, Wv, wt, WT_E, DIN, DA);
  transpose_f32<<<dim3(DIN / 32, DA / 32, 1), dim3(32, 8), 0, stream>>>(
      Wo, Wo, Wo, woT, 0, DA, DIN);

  // 3. projections (8-phase 256x256): z = Q1,K1,Q2,K2,V1,V2
  {
    G8Args<f16> a{};
    const float* bs[3] = {bq, bk, bv};
    for (int zi = 0; zi < 6; ++zi) {
      int which = (zi < 4) ? (zi & 1) : 2;
      int src = (zi < 4) ? (zi >> 1) : (zi - 4);
      a.A[zi] = in_hf + (size_t)src * IN_E;
      a.B[zi] = wt + (size_t)which * WT_E;
      a.bias[zi] = bs[which];
      a.C[zi] = (zi < 4) ? (void*)(qk + (size_t)zi * QS) : (void*)(vv + (size_t)(zi - 4) * QS);
      a.storebf[zi] = (zi >= 4);
      a.k0[zi] = 0;
    }
    a.lda = DIN; a.ldb = DIN; a.ldc = DA;
    g8<f16, 0, 256, 16><<<dim3(2, 16, 6), dim3(512), 0, stream>>>(a);
  }

  // 4. V -> Vt ([4096,512] -> [512][4096])
  transpose_b16<<<dim3(DA / 32, NROWS / 32, 2), dim3(32, 8), 0, stream>>>(
      vv, QS, vt, QS, NROWS, DA);

  // 5. P = exp(Q @ K^T) (8-phase 256x256): z=0: Q1@K2^T, z=1: Q2@K1^T
  {
    G8Args<f16> a{};
    a.A[0] = qk + 0 * QS; a.B[0] = qk + 3 * QS; a.C[0] = P;
    a.A[1] = qk + 2 * QS; a.B[1] = qk + 1 * QS; a.C[1] = P + PS;
    a.k0[0] = a.k0[1] = 0;
    a.lda = DA; a.ldb = DA; a.ldc = NROWS;
    g8<f16, 1, 256, 8><<<dim3(16, 16, 2), dim3(512), 0, stream>>>(a);
  }

  // 6. PV split-K partials (8-phase 256x128): z = split*2 + pair
  {
    G8Args<bf16> a{};
    for (int i = 0; i < 4; ++i) {
      int pair = i & 1, s = i >> 1;
      a.A[i] = P + (size_t)pair * PS;
      a.B[i] = vt + (size_t)(pair ^ 1) * QS;
      a.C[i] = pO + (size_t)i * QS;
      a.rsO[i] = prs + (size_t)i * NROWS;
      a.k0[i] = s * 2048;
      a.storebf[i] = 0;
    }
    a.lda = NROWS; a.ldb = NROWS; a.ldc = DA;
    g8<bf16, 2, 128, 32><<<dim3(4, 16, 4), dim3(512), 0, stream>>>(a);
  }

  // 7. merge partials -> mid (f16)
  merge_kernel<<<dim3((unsigned)(2 * QS / 1024)), dim3(256), 0, stream>>>(pO, prs, mid);

  // 8. out = mid @ Wo + bo (f32)
  out_gemm<<<dim3(DIN / 128, NROWS / 128, 2), dim3(512), 0, stream>>>(mid, woT, bo, out);
}

// Round 9
// 204.619 us; speedup vs baseline: 4.2205x; 4.2205x over previous
//
#include <hip/hip_runtime.h>

typedef __bf16 bf16;
typedef _Float16 f16;
typedef __bf16 bf16x8 __attribute__((ext_vector_type(8)));
typedef _Float16 f16x8 __attribute__((ext_vector_type(8)));
typedef _Float16 f16x4 __attribute__((ext_vector_type(4)));
typedef float f32x4 __attribute__((ext_vector_type(4)));

#define NROWS 4096
#define DIN 1024
#define DA 512

template <typename T> struct V8;
template <> struct V8<f16> { using type = f16x8; };
template <> struct V8<bf16> { using type = bf16x8; };

__device__ __forceinline__ f32x4 mfma16(f16x8 a, f16x8 b, f32x4 c) {
  return __builtin_amdgcn_mfma_f32_16x16x32_f16(a, b, c, 0, 0, 0);
}
__device__ __forceinline__ f32x4 mfma16(bf16x8 a, bf16x8 b, f32x4 c) {
  return __builtin_amdgcn_mfma_f32_16x16x32_bf16(a, b, c, 0, 0, 0);
}

__device__ __forceinline__ void gload_lds16(const void* g, void* l) {
  __builtin_amdgcn_global_load_lds((const __attribute__((address_space(1))) void*)g,
                                   (__attribute__((address_space(3))) void*)l, 16, 0, 0);
}

// ---------------- prep kernels ----------------

__global__ void cast_kernel(const float* __restrict__ s1, const float* __restrict__ s2,
                            f16* __restrict__ d1, f16* __restrict__ d2, int n) {
  const float* s = blockIdx.z ? s2 : s1;
  f16* d = blockIdx.z ? d2 : d1;
  int i = (blockIdx.x * blockDim.x + threadIdx.x) * 4;
  if (i < n) {
    float4 v = *(const float4*)(s + i);
    f16x4 o;
    o[0] = (f16)v.x; o[1] = (f16)v.y; o[2] = (f16)v.z; o[3] = (f16)v.w;
    *(f16x4*)(d + i) = o;
  }
}

// dst[c][r] = (f16) src[r][c]
__global__ void transpose_f32(const float* __restrict__ w0, const float* __restrict__ w1,
                              const float* __restrict__ w2, f16* __restrict__ dst,
                              size_t dstride, int rows, int cols) {
  const float* s = blockIdx.z == 0 ? w0 : (blockIdx.z == 1 ? w1 : w2);
  f16* d = dst + (size_t)blockIdx.z * dstride;
  __shared__ float tile[32][33];
  int bc = blockIdx.x * 32, br = blockIdx.y * 32;
  int tx = threadIdx.x, ty = threadIdx.y;
  for (int i = ty; i < 32; i += 8)
    tile[i][tx] = s[(size_t)(br + i) * cols + bc + tx];
  __syncthreads();
  for (int i = ty; i < 32; i += 8)
    d[(size_t)(bc + i) * rows + br + tx] = (f16)tile[tx][i];
}

// bf16 [rows,cols] -> bf16 [cols][rows]
__global__ void transpose_b16(const bf16* __restrict__ src, size_t sstride,
                              bf16* __restrict__ dst, size_t dstride, int rows, int cols) {
  const bf16* s = src + (size_t)blockIdx.z * sstride;
  bf16* d = dst + (size_t)blockIdx.z * dstride;
  __shared__ float tile[32][33];
  int bc = blockIdx.x * 32, br = blockIdx.y * 32;
  int tx = threadIdx.x, ty = threadIdx.y;
  for (int i = ty; i < 32; i += 8)
    tile[i][tx] = (float)s[(size_t)(br + i) * cols + bc + tx];
  __syncthreads();
  for (int i = ty; i < 32; i += 8)
    d[(size_t)(bc + i) * rows + br + tx] = (bf16)tile[tx][i];
}

// sum the 64 per-column-chunk rowsum partials -> prsT[z][row]
__global__ void rowsum_reduce(const float* __restrict__ prsP, float* __restrict__ prsT) {
  int i = blockIdx.x * 256 + threadIdx.x;  // 0..8191 = z*4096 + row
  int z = i >> 12, row = i & 4095;
  const float* p = prsP + (size_t)z * 64 * NROWS + row;
  float s = 0.f;
#pragma unroll
  for (int j = 0; j < 64; ++j) s += p[(size_t)j * NROWS];
  prsT[i] = s;
}

// merge split-K PV partials: mid = (pO[z]+pO[2+z]) / prsT[z][row], f16
__global__ void merge_kernel(const float* __restrict__ pO, const float* __restrict__ prsT,
                             f16* __restrict__ mid) {
  const size_t QS = (size_t)NROWS * DA;
  size_t e = ((size_t)blockIdx.x * blockDim.x + threadIdx.x) * 4;
  int z = (int)(e / QS);
  size_t rem = e - (size_t)z * QS;
  int row = (int)(rem / DA);
  float4 a = *(const float4*)(pO + (size_t)z * QS + rem);
  float4 b = *(const float4*)(pO + (size_t)(2 + z) * QS + rem);
  float inv = 1.0f / prsT[z * NROWS + row];
  f16x4 o;
  o[0] = (f16)((a.x + b.x) * inv);
  o[1] = (f16)((a.y + b.y) * inv);
  o[2] = (f16)((a.z + b.z) * inv);
  o[3] = (f16)((a.w + b.w) * inv);
  *(f16x4*)(mid + (size_t)z * QS + rem) = o;
}

// ---------------- 8-phase 256-row GEMM template ----------------
// C[256 x BN tile] = A[M,K] @ Bt[N,K]^T over K window [k0, k0+NT*64).
// 8 waves (2M x 4N), BK=64, M-interleaved wave frags. Double-buffered LDS,
// 1-tile-ahead staging, counted vmcnt; XOR swizzle chunk^=(row&7) with
// inverse-swizzled global source. BN=256 stages [B0,B1,A0,A1]; BN=128 [B0,A0,A1].
// EPI 0: +bias, store f16/bf16 per storebf[z]
// EPI 1: exp(), store bf16 + per-(blkN,wn) f32 rowsum partials to rsO[z]
// EPI 2: split-K partial: f32 acc to C (no rowsum — avoids VGPR spill)

template <typename TIN>
struct G8Args {
  const TIN* A[6];
  const TIN* B[6];
  const float* bias[6];
  void* C[6];
  float* rsO[6];
  int k0[6];
  int storebf[6];
  int lda, ldb, ldc;
};

template <typename TIN, int EPI, int BN, int NT>
__global__ __launch_bounds__(512, 1) void g8(G8Args<TIN> args) {
  using vec8 = typename V8<TIN>::type;
  constexpr int NFR = BN / 64;           // 4 or 2 n-frags per wave
  constexpr int BBUF = BN * 128;         // B bytes per buffer
  constexpr int BUFSZ = 32768 + BBUF;
  __shared__ __align__(16) char smem[2 * BUFSZ];

  const int z = blockIdx.z;
  const TIN* __restrict__ A = args.A[z];
  const TIN* __restrict__ B = args.B[z];
  const int lda = args.lda, ldb = args.ldb;
  const int k0 = args.k0[z];

  // T1 XCD-aware bijective swizzle (all grids here are %8==0 per z)
  int blkM, blkN;
  {
    const int gx = gridDim.x;
    const int nwg = gx * gridDim.y;
    const int lin = blockIdx.y * gx + blockIdx.x;
    const int q = nwg >> 3;
    const int nl = (lin & 7) * q + (lin >> 3);
    blkN = nl % gx;
    blkM = nl / gx;
  }

  const int tid = threadIdx.x;
  const int w = tid >> 6, lane = tid & 63;
  const int wm = w & 1, wn = w >> 1;     // 2M x 4N
  const int lr = lane & 15, lh = lane >> 4;

  const TIN* Abase = A + (size_t)blkM * 256 * lda;
  const TIN* Bbase = B + (size_t)blkN * BN * ldb;

  f32x4 acc[8][NFR] = {};
  vec8 af[2][2], bfr[NFR][2];

#define STAGE_A(buf, hf, kt)                                                    \
  {                                                                             \
    char* dst_ = smem + (buf)*BUFSZ + (hf)*16384;                               \
    const TIN* src_ = Abase + (size_t)((hf)*128) * lda + (kt);                  \
    _Pragma("unroll")                                                           \
    for (int i_ = 0; i_ < 2; ++i_) {                                            \
      int c_ = i_ * 512 + tid;                                                  \
      int r_ = c_ >> 3, q_ = c_ & 7;                                            \
      gload_lds16(src_ + (size_t)r_ * lda + ((q_ ^ (r_ & 7)) << 3),             \
                  dst_ + c_ * 16);                                              \
    }                                                                           \
  }
#define STAGE_B(buf, hf, kt)                                                    \
  {                                                                             \
    char* dst_ = smem + (buf)*BUFSZ + 32768 + (hf)*16384;                       \
    const TIN* src_ = Bbase + (size_t)((hf)*128) * ldb + (kt);                  \
    _Pragma("unroll")                                                           \
    for (int i_ = 0; i_ < 2; ++i_) {                                            \
      int c_ = i_ * 512 + tid;                                                  \
      int r_ = c_ >> 3, q_ = c_ & 7;                                            \
      gload_lds16(src_ + (size_t)r_ * ldb + ((q_ ^ (r_ & 7)) << 3),             \
                  dst_ + c_ * 16);                                              \
    }                                                                           \
  }
#define LDA_PHASE(buf, p)                                                       \
  {                                                                             \
    char* Ab_ = smem + (buf)*BUFSZ;                                             \
    _Pragma("unroll")                                                           \
    for (int fi_ = 0; fi_ < 2; ++fi_) {                                         \
      int row_ = (((p)*2 + fi_) * 2 + wm) * 16 + lr;                            \
      _Pragma("unroll")                                                         \
      for (int kk_ = 0; kk_ < 2; ++kk_) {                                       \
        int cc_ = (kk_ * 4 + lh) ^ (row_ & 7);                                  \
        af[fi_][kk_] = *(const vec8*)(Ab_ + row_ * 128 + cc_ * 16);             \
      }                                                                         \
    }                                                                           \
  }
#define LDB_ALL(buf)                                                            \
  {                                                                             \
    char* Bb_ = smem + (buf)*BUFSZ + 32768;                                     \
    _Pragma("unroll")                                                           \
    for (int n_ = 0; n_ < NFR; ++n_) {                                          \
      int row_ = wn * (BN / 4) + n_ * 16 + lr;                                  \
      _Pragma("unroll")                                                         \
      for (int kk_ = 0; kk_ < 2; ++kk_) {                                       \
        int cc_ = (kk_ * 4 + lh) ^ (row_ & 7);                                  \
        bfr[n_][kk_] = *(const vec8*)(Bb_ + row_ * 128 + cc_ * 16);             \
      }                                                                         \
    }                                                                           \
  }
#define MFMA_PHASE(p)                                                           \
  {                                                                             \
    _Pragma("unroll")                                                           \
    for (int fi_ = 0; fi_ < 2; ++fi_) {                                         \
      _Pragma("unroll")                                                         \
      for (int n_ = 0; n_ < NFR; ++n_) {                                        \
        _Pragma("unroll")                                                       \
        for (int kk_ = 0; kk_ < 2; ++kk_)                                       \
          acc[(p)*2 + fi_][n_] = mfma16(af[fi_][kk_], bfr[n_][kk_],             \
                                        acc[(p)*2 + fi_][n_]);                  \
      }                                                                         \
    }                                                                           \
  }
#define BAR() __builtin_amdgcn_s_barrier()
#define LGK0()                                          \
  asm volatile("s_waitcnt lgkmcnt(0)" ::: "memory");    \
  __builtin_amdgcn_sched_barrier(0)

  // prologue
  if constexpr (NFR == 4) {
    STAGE_B(0, 0, k0); STAGE_B(0, 1, k0); STAGE_A(0, 0, k0); STAGE_A(0, 1, k0);
  } else {
    STAGE_B(0, 0, k0); STAGE_A(0, 0, k0); STAGE_A(0, 1, k0);
  }
  asm volatile("s_waitcnt vmcnt(2)" ::: "memory");  // last A-half still in flight
  BAR();

  for (int t = 0; t < NT; ++t) {
    const int cur = t & 1, nxt = cur ^ 1;
    const int ktn = k0 + (t + 1) * 64;
    const bool st = (t < NT - 1);
    // ---- ph0: uses B + A-half0 ----
    if (st) { STAGE_B(nxt, 0, ktn); }
    LDB_ALL(cur);
    LDA_PHASE(cur, 0);
    BAR(); LGK0();
    __builtin_amdgcn_s_setprio(1); MFMA_PHASE(0); __builtin_amdgcn_s_setprio(0);
    BAR();
    // ---- ph1: uses A-half0 ----
    if (st) {
      if constexpr (NFR == 4) { STAGE_B(nxt, 1, ktn); } else { STAGE_A(nxt, 0, ktn); }
    }
    LDA_PHASE(cur, 1);
    BAR(); LGK0();
    __builtin_amdgcn_s_setprio(1); MFMA_PHASE(1); __builtin_amdgcn_s_setprio(0);
    if (st) { asm volatile("s_waitcnt vmcnt(4)" ::: "memory"); }  // A-half1(t) landed
    else    { asm volatile("s_waitcnt vmcnt(0)" ::: "memory"); }
    BAR();
    // ---- ph2: uses A-half1 ----
    if (st) {
      if constexpr (NFR == 4) { STAGE_A(nxt, 0, ktn); } else { STAGE_A(nxt, 1, ktn); }
    }
    LDA_PHASE(cur, 2);
    BAR(); LGK0();
    __builtin_amdgcn_s_setprio(1); MFMA_PHASE(2); __builtin_amdgcn_s_setprio(0);
    BAR();
    // ---- ph3: uses A-half1 ----
    if (st) {
      if constexpr (NFR == 4) { STAGE_A(nxt, 1, ktn); }
    }
    LDA_PHASE(cur, 3);
    BAR(); LGK0();
    __builtin_amdgcn_s_setprio(1); MFMA_PHASE(3); __builtin_amdgcn_s_setprio(0);
    if (st) { asm volatile("s_waitcnt vmcnt(2)" ::: "memory"); }  // next B+A0 landed
    BAR();
  }

  // ---- epilogue ----
  const int row0 = blkM * 256;
  const int col0 = blkN * BN + wn * (BN / 4);
  const int ldc = args.ldc;
  if constexpr (EPI == 1) {
    // exp + store + per-(blkN,wn) rowsum partials (sum over this wave's 64 cols)
#pragma unroll
    for (int a = 0; a < 8; ++a) {
      float rsv[4] = {0.f, 0.f, 0.f, 0.f};
#pragma unroll
      for (int n = 0; n < NFR; ++n) {
#pragma unroll
        for (int rr = 0; rr < 4; ++rr) {
          int row = row0 + (a * 2 + wm) * 16 + lh * 4 + rr;
          int col = col0 + n * 16 + lr;
          float e = __expf(acc[a][n][rr]);
          ((bf16*)args.C[z])[(size_t)row * ldc + col] = (bf16)e;
          rsv[rr] += e;
        }
      }
#pragma unroll
      for (int rr = 0; rr < 4; ++rr) {
        float s = rsv[rr];
        s += __shfl_xor(s, 1);
        s += __shfl_xor(s, 2);
        s += __shfl_xor(s, 4);
        s += __shfl_xor(s, 8);
        if (lr == 0) {
          int row = row0 + (a * 2 + wm) * 16 + lh * 4 + rr;
          args.rsO[z][((size_t)blkN * 4 + wn) * NROWS + row] = s;
        }
      }
    }
  } else {
#pragma unroll
    for (int a = 0; a < 8; ++a) {
#pragma unroll
      for (int n = 0; n < NFR; ++n) {
#pragma unroll
        for (int rr = 0; rr < 4; ++rr) {
          int row = row0 + (a * 2 + wm) * 16 + lh * 4 + rr;
          int col = col0 + n * 16 + lr;
          float v = acc[a][n][rr];
          if constexpr (EPI == 0) {
            float b = v + args.bias[z][col];
            if (args.storebf[z])
              ((bf16*)args.C[z])[(size_t)row * ldc + col] = (bf16)b;
            else
              ((f16*)args.C[z])[(size_t)row * ldc + col] = (f16)b;
          } else {
            ((float*)args.C[z])[(size_t)row * ldc + col] = v;
          }
        }
      }
    }
  }
#undef STAGE_A
#undef STAGE_B
#undef LDA_PHASE
#undef LDB_ALL
#undef MFMA_PHASE
#undef BAR
#undef LGK0
}

// ---------------- out GEMM (128x128, 2-phase) ----------------

__global__ __launch_bounds__(512) void out_gemm(const f16* __restrict__ mid,
                                                const f16* __restrict__ woT,
                                                const float* __restrict__ bo,
                                                float* __restrict__ out) {
  __shared__ __align__(16) f16 As[128 * 64];
  __shared__ __align__(16) f16 Bs[128 * 64];

  const int z = blockIdx.z;
  const f16* __restrict__ Ag = mid + (size_t)z * NROWS * DA;
  float* __restrict__ Cg = out + (size_t)z * NROWS * DIN;

  int blkM, blkN;
  {
    const int gx = gridDim.x;
    const int nwg = gx * gridDim.y;
    const int lin = blockIdx.y * gx + blockIdx.x;
    const int q = nwg >> 3;
    const int nl = (lin & 7) * q + (lin >> 3);
    blkN = nl % gx;
    blkM = nl / gx;
  }

  const int tid = threadIdx.x;
  const int w = tid >> 6, lane = tid & 63;
  const int wr = w >> 2, wc = w & 3;
  const int lrow = lane & 15, lhi = lane >> 4;

  const f16* Abase = Ag + (size_t)blkM * 128 * DA;
  const f16* Bbase = woT + (size_t)blkN * 128 * DA;

  f32x4 acc[4][2] = {};

  for (int kt = 0; kt < DA; kt += 64) {
#pragma unroll
    for (int it = 0; it < 2; ++it) {
      int cidx = (it * 8 + w) * 64 + lane;
      int row = cidx >> 3;
      int col = (cidx & 7) << 3;
      gload_lds16(Abase + (size_t)row * DA + kt + col, (char*)As + (size_t)cidx * 16);
    }
#pragma unroll
    for (int it = 0; it < 2; ++it) {
      int cidx = (it * 8 + w) * 64 + lane;
      int row = cidx >> 3;
      int col = (cidx & 7) << 3;
      gload_lds16(Bbase + (size_t)row * DA + kt + col, (char*)Bs + (size_t)cidx * 16);
    }
    __syncthreads();

    f16x8 af[4][2], bfr[2][2];
#pragma unroll
    for (int m = 0; m < 4; ++m)
#pragma unroll
      for (int kk = 0; kk < 2; ++kk)
        af[m][kk] = *(const f16x8*)&As[(wr * 64 + m * 16 + lrow) * 64 + kk * 32 + lhi * 8];
#pragma unroll
    for (int n = 0; n < 2; ++n)
#pragma unroll
      for (int kk = 0; kk < 2; ++kk)
        bfr[n][kk] = *(const f16x8*)&Bs[(wc * 32 + n * 16 + lrow) * 64 + kk * 32 + lhi * 8];

#pragma unroll
    for (int m = 0; m < 4; ++m)
#pragma unroll
      for (int n = 0; n < 2; ++n)
#pragma unroll
        for (int kk = 0; kk < 2; ++kk)
          acc[m][n] = mfma16(af[m][kk], bfr[n][kk], acc[m][n]);
    __syncthreads();
  }

  const int row0 = blkM * 128 + wr * 64;
  const int col0 = blkN * 128 + wc * 32;
#pragma unroll
  for (int m = 0; m < 4; ++m)
#pragma unroll
    for (int n = 0; n < 2; ++n)
#pragma unroll
      for (int r = 0; r < 4; ++r) {
        int row = row0 + m * 16 + lhi * 4 + r;
        int col = col0 + n * 16 + lrow;
        Cg[(size_t)row * DIN + col] = acc[m][n][r] + bo[col];
      }
}

// ---------------- launch ----------------

extern "C" void kernel_launch(void* const* d_in, const int* in_sizes, int n_in,
                              void* d_out, int out_size, void* d_ws, size_t ws_size,
                              hipStream_t stream) {
  const float* in1 = (const float*)d_in[0];
  const float* in2 = (const float*)d_in[1];
  const float* Wq = (const float*)d_in[2];
  const float* bq = (const float*)d_in[3];
  const float* Wk = (const float*)d_in[4];
  const float* bk = (const float*)d_in[5];
  const float* Wv = (const float*)d_in[6];
  const float* bv = (const float*)d_in[7];
  const float* Wo = (const float*)d_in[8];
  const float* bo = (const float*)d_in[9];
  float* out = (float*)d_out;

  const size_t IN_E = (size_t)NROWS * DIN;   // 4M
  const size_t WT_E = (size_t)DA * DIN;      // 512K
  const size_t QS = (size_t)NROWS * DA;      // 2M
  const size_t PS = (size_t)NROWS * NROWS;   // 16M

  f16* qk = (f16*)d_ws;                      // 16 MB (dead after QK)
  f16* in_hf = qk + 4 * QS;                  // 16 MB (dead after proj)
  bf16* vv = (bf16*)(in_hf + 2 * IN_E);      // 8 MB (dead after transpose)
  f16* wt = (f16*)(vv + 2 * QS);             // 3 MB
  f16* woT = wt + 3 * WT_E;                  // 1 MB
  bf16* vt = (bf16*)(woT + WT_E);            // 8 MB
  bf16* P = vt + 2 * QS;                     // 64 MB
  f16* mid = (f16*)(P + 2 * PS);             // 8 MB
  float* pO = (float*)d_ws;                  // 32 MB, aliases qk+in_hf (dead then)
  float* prsP = (float*)vv;                  // 2 MB rowsum partials, aliases vv
  float* prsT = prsP + 2 * 64 * NROWS;       // 32 KB totals

  // 1. cast inputs to fp16
  cast_kernel<<<dim3((unsigned)(IN_E / 1024), 1, 2), dim3(256), 0, stream>>>(
      in1, in2, in_hf, in_hf + IN_E, (int)IN_E);

  // 2. transpose-cast weights
  transpose_f32<<<dim3(DA / 32, DIN / 32, 3), dim3(32, 8), 0, stream>>>(
      Wq, Wk, Wv, wt, WT_E, DIN, DA);
  transpose_f32<<<dim3(DIN / 32, DA / 32, 1), dim3(32, 8), 0, stream>>>(
      Wo, Wo, Wo, woT, 0, DA, DIN);

  // 3. projections (8-phase 256x256): z = Q1,K1,Q2,K2,V1,V2
  {
    G8Args<f16> a{};
    const float* bs[3] = {bq, bk, bv};
    for (int zi = 0; zi < 6; ++zi) {
      int which = (zi < 4) ? (zi & 1) : 2;
      int src = (zi < 4) ? (zi >> 1) : (zi - 4);
      a.A[zi] = in_hf + (size_t)src * IN_E;
      a.B[zi] = wt + (size_t)which * WT_E;
      a.bias[zi] = bs[which];
      a.C[zi] = (zi < 4) ? (void*)(qk + (size_t)zi * QS) : (void*)(vv + (size_t)(zi - 4) * QS);
      a.storebf[zi] = (zi >= 4);
      a.k0[zi] = 0;
    }
    a.lda = DIN; a.ldb = DIN; a.ldc = DA;
    g8<f16, 0, 256, 16><<<dim3(2, 16, 6), dim3(512), 0, stream>>>(a);
  }

  // 4. V -> Vt ([4096,512] -> [512][4096])
  transpose_b16<<<dim3(DA / 32, NROWS / 32, 2), dim3(32, 8), 0, stream>>>(
      vv, QS, vt, QS, NROWS, DA);

  // 5. P = exp(Q @ K^T) + rowsum partials (8-phase 256x256)
  {
    G8Args<f16> a{};
    a.A[0] = qk + 0 * QS; a.B[0] = qk + 3 * QS; a.C[0] = P;
    a.A[1] = qk + 2 * QS; a.B[1] = qk + 1 * QS; a.C[1] = P + PS;
    a.rsO[0] = prsP;
    a.rsO[1] = prsP + (size_t)64 * NROWS;
    a.k0[0] = a.k0[1] = 0;
    a.lda = DA; a.ldb = DA; a.ldc = NROWS;
    g8<f16, 1, 256, 8><<<dim3(16, 16, 2), dim3(512), 0, stream>>>(a);
  }

  // 5b. reduce rowsum partials
  rowsum_reduce<<<dim3(32), dim3(256), 0, stream>>>(prsP, prsT);

  // 6. PV split-K partials (8-phase 256x128, no rowsum): z = split*2 + pair
  {
    G8Args<bf16> a{};
    for (int i = 0; i < 4; ++i) {
      int pair = i & 1, s = i >> 1;
      a.A[i] = P + (size_t)pair * PS;
      a.B[i] = vt + (size_t)(pair ^ 1) * QS;
      a.C[i] = pO + (size_t)i * QS;
      a.k0[i] = s * 2048;
      a.storebf[i] = 0;
    }
    a.lda = NROWS; a.ldb = NROWS; a.ldc = DA;
    g8<bf16, 2, 128, 32><<<dim3(4, 16, 4), dim3(512), 0, stream>>>(a);
  }

  // 7. merge partials -> mid (f16)
  merge_kernel<<<dim3((unsigned)(2 * QS / 1024)), dim3(256), 0, stream>>>(pO, prsT, mid);

  // 8. out = mid @ Wo + bo (f32)
  out_gemm<<<dim3(DIN / 128, NROWS / 128, 2), dim3(512), 0, stream>>>(mid, woT, bo, out);
}

// Round 10
// 199.974 us; speedup vs baseline: 4.3185x; 1.0232x over previous
//
#include <hip/hip_runtime.h>

typedef __bf16 bf16;
typedef _Float16 f16;
typedef __bf16 bf16x8 __attribute__((ext_vector_type(8)));
typedef _Float16 f16x8 __attribute__((ext_vector_type(8)));
typedef _Float16 f16x4 __attribute__((ext_vector_type(4)));
typedef float f32x4 __attribute__((ext_vector_type(4)));

#define NROWS 4096
#define DIN 1024
#define DA 512

template <typename T> struct V8;
template <> struct V8<f16> { using type = f16x8; };
template <> struct V8<bf16> { using type = bf16x8; };

__device__ __forceinline__ f32x4 mfma16(f16x8 a, f16x8 b, f32x4 c) {
  return __builtin_amdgcn_mfma_f32_16x16x32_f16(a, b, c, 0, 0, 0);
}
__device__ __forceinline__ f32x4 mfma16(bf16x8 a, bf16x8 b, f32x4 c) {
  return __builtin_amdgcn_mfma_f32_16x16x32_bf16(a, b, c, 0, 0, 0);
}

__device__ __forceinline__ void gload_lds16(const void* g, void* l) {
  __builtin_amdgcn_global_load_lds((const __attribute__((address_space(1))) void*)g,
                                   (__attribute__((address_space(3))) void*)l, 16, 0, 0);
}

template <int N> __device__ __forceinline__ void vmcnt_wait() {
  if constexpr (N == 0) asm volatile("s_waitcnt vmcnt(0)" ::: "memory");
  else if constexpr (N == 1) asm volatile("s_waitcnt vmcnt(1)" ::: "memory");
  else if constexpr (N == 2) asm volatile("s_waitcnt vmcnt(2)" ::: "memory");
  else if constexpr (N == 4) asm volatile("s_waitcnt vmcnt(4)" ::: "memory");
}

// ---------------- prep kernels ----------------

__global__ void cast_kernel(const float* __restrict__ s1, const float* __restrict__ s2,
                            f16* __restrict__ d1, f16* __restrict__ d2, int n) {
  const float* s = blockIdx.z ? s2 : s1;
  f16* d = blockIdx.z ? d2 : d1;
  int i = (blockIdx.x * blockDim.x + threadIdx.x) * 4;
  if (i < n) {
    float4 v = *(const float4*)(s + i);
    f16x4 o;
    o[0] = (f16)v.x; o[1] = (f16)v.y; o[2] = (f16)v.z; o[3] = (f16)v.w;
    *(f16x4*)(d + i) = o;
  }
}

// dst[c][r] = (f16) src[r][c]
__global__ void transpose_f32(const float* __restrict__ w0, const float* __restrict__ w1,
                              const float* __restrict__ w2, f16* __restrict__ dst,
                              size_t dstride, int rows, int cols) {
  const float* s = blockIdx.z == 0 ? w0 : (blockIdx.z == 1 ? w1 : w2);
  f16* d = dst + (size_t)blockIdx.z * dstride;
  __shared__ float tile[32][33];
  int bc = blockIdx.x * 32, br = blockIdx.y * 32;
  int tx = threadIdx.x, ty = threadIdx.y;
  for (int i = ty; i < 32; i += 8)
    tile[i][tx] = s[(size_t)(br + i) * cols + bc + tx];
  __syncthreads();
  for (int i = ty; i < 32; i += 8)
    d[(size_t)(bc + i) * rows + br + tx] = (f16)tile[tx][i];
}

// bf16 [rows,cols] -> bf16 [cols][rows]
__global__ void transpose_b16(const bf16* __restrict__ src, size_t sstride,
                              bf16* __restrict__ dst, size_t dstride, int rows, int cols) {
  const bf16* s = src + (size_t)blockIdx.z * sstride;
  bf16* d = dst + (size_t)blockIdx.z * dstride;
  __shared__ float tile[32][33];
  int bc = blockIdx.x * 32, br = blockIdx.y * 32;
  int tx = threadIdx.x, ty = threadIdx.y;
  for (int i = ty; i < 32; i += 8)
    tile[i][tx] = (float)s[(size_t)(br + i) * cols + bc + tx];
  __syncthreads();
  for (int i = ty; i < 32; i += 8)
    d[(size_t)(bc + i) * rows + br + tx] = (bf16)tile[tx][i];
}

// sum the 64 per-column-chunk rowsum partials -> prsT[z][row]
__global__ void rowsum_reduce(const float* __restrict__ prsP, float* __restrict__ prsT) {
  int i = blockIdx.x * 256 + threadIdx.x;  // 0..8191 = z*4096 + row
  int z = i >> 12, row = i & 4095;
  const float* p = prsP + (size_t)z * 64 * NROWS + row;
  float s = 0.f;
#pragma unroll
  for (int j = 0; j < 64; ++j) s += p[(size_t)j * NROWS];
  prsT[i] = s;
}

// merge split-K PV partials: mid = (pO[z]+pO[2+z]) / prsT[z][row], f16
__global__ void merge_kernel(const float* __restrict__ pO, const float* __restrict__ prsT,
                             f16* __restrict__ mid) {
  const size_t QS = (size_t)NROWS * DA;
  size_t e = ((size_t)blockIdx.x * blockDim.x + threadIdx.x) * 4;
  int z = (int)(e / QS);
  size_t rem = e - (size_t)z * QS;
  int row = (int)(rem / DA);
  float4 a = *(const float4*)(pO + (size_t)z * QS + rem);
  float4 b = *(const float4*)(pO + (size_t)(2 + z) * QS + rem);
  float inv = 1.0f / prsT[z * NROWS + row];
  f16x4 o;
  o[0] = (f16)((a.x + b.x) * inv);
  o[1] = (f16)((a.y + b.y) * inv);
  o[2] = (f16)((a.z + b.z) * inv);
  o[3] = (f16)((a.w + b.w) * inv);
  *(f16x4*)(mid + (size_t)z * QS + rem) = o;
}

// ---------------- 8-phase 256-row GEMM template ----------------
// C[256 x BN] = A[M,K] @ Bt[N,K]^T over K window [k0, k0+NT*BK).
// 8 waves (2M x 4N), M-interleaved wave frags (phase p consumes A-rows
// p*64..p*64+63). Double-buffered LDS, 1-tile-ahead staging with counted
// vmcnt (units of IPU=BK/32 gload-rounds); XOR swizzle chunk^=(row&SWM) with
// inverse-swizzled global source. NFR==4 stages [B0,B1,A0,A1]; NFR==2 [B0,A0,A1].
// EPI 0: +bias, store f16/bf16 per storebf[z]
// EPI 1: exp(), store bf16 + per-(blkN,wn) f32 rowsum partials to rsO[z]
// EPI 2: split-K partial: f32 acc to C
// EPI 3: +bias, store f32

template <typename TIN>
struct G8Args {
  const TIN* A[6];
  const TIN* B[6];
  const float* bias[6];
  void* C[6];
  float* rsO[6];
  int k0[6];
  int storebf[6];
  int lda, ldb, ldc;
};

template <typename TIN, int EPI, int BN, int NT, int BK = 64, int MINW = 1>
__global__ __launch_bounds__(512, MINW) void g8(G8Args<TIN> args) {
  using vec8 = typename V8<TIN>::type;
  constexpr int NFR = BN / 64;           // 4 or 2 n-frags per wave
  constexpr int KK = BK / 32;            // mfma k-steps per frag (1 or 2)
  constexpr int RB = BK * 2;             // LDS row bytes
  constexpr int CPR = RB / 16;           // 16B chunks per row
  constexpr int SWM = CPR - 1;           // swizzle mask
  constexpr int ABUF = 256 * RB;         // A bytes/buffer
  constexpr int BBUF = BN * RB;          // B bytes/buffer
  constexpr int BUFSZ = ABUF + BBUF;
  constexpr int IPU = ABUF / 2 / 8192;   // gload-rounds per 128-row stage unit
  __shared__ __align__(16) char smem[2 * BUFSZ];

  const int z = blockIdx.z;
  const TIN* __restrict__ A = args.A[z];
  const TIN* __restrict__ B = args.B[z];
  const int lda = args.lda, ldb = args.ldb;
  const int k0 = args.k0[z];

  // T1 XCD-aware bijective swizzle (all grids here are %8==0 per z)
  int blkM, blkN;
  {
    const int gx = gridDim.x;
    const int nwg = gx * gridDim.y;
    const int lin = blockIdx.y * gx + blockIdx.x;
    const int q = nwg >> 3;
    const int nl = (lin & 7) * q + (lin >> 3);
    blkN = nl % gx;
    blkM = nl / gx;
  }

  const int tid = threadIdx.x;
  const int w = tid >> 6, lane = tid & 63;
  const int wm = w & 1, wn = w >> 1;     // 2M x 4N
  const int lr = lane & 15, lh = lane >> 4;

  const TIN* Abase = A + (size_t)blkM * 256 * lda;
  const TIN* Bbase = B + (size_t)blkN * BN * ldb;

  f32x4 acc[8][NFR] = {};
  vec8 af[2][KK], bfr[NFR][KK];

#define STAGE_A(buf, hf, kt)                                                    \
  {                                                                             \
    char* dst_ = smem + (buf)*BUFSZ + (hf)*(ABUF / 2);                          \
    const TIN* src_ = Abase + (size_t)((hf)*128) * lda + (kt);                  \
    _Pragma("unroll")                                                           \
    for (int i_ = 0; i_ < IPU; ++i_) {                                          \
      int c_ = i_ * 512 + tid;                                                  \
      int r_ = c_ / CPR, q_ = c_ % CPR;                                         \
      gload_lds16(src_ + (size_t)r_ * lda + ((q_ ^ (r_ & SWM)) << 3),           \
                  dst_ + c_ * 16);                                              \
    }                                                                           \
  }
#define STAGE_B(buf, hf, kt)                                                    \
  {                                                                             \
    char* dst_ = smem + (buf)*BUFSZ + ABUF + (hf)*(ABUF / 2);                   \
    const TIN* src_ = Bbase + (size_t)((hf)*128) * ldb + (kt);                  \
    _Pragma("unroll")                                                           \
    for (int i_ = 0; i_ < IPU; ++i_) {                                          \
      int c_ = i_ * 512 + tid;                                                  \
      int r_ = c_ / CPR, q_ = c_ % CPR;                                         \
      gload_lds16(src_ + (size_t)r_ * ldb + ((q_ ^ (r_ & SWM)) << 3),           \
                  dst_ + c_ * 16);                                              \
    }                                                                           \
  }
#define LDA_PHASE(buf, p)                                                       \
  {                                                                             \
    char* Ab_ = smem + (buf)*BUFSZ;                                             \
    _Pragma("unroll")                                                           \
    for (int fi_ = 0; fi_ < 2; ++fi_) {                                         \
      int row_ = (((p)*2 + fi_) * 2 + wm) * 16 + lr;                            \
      _Pragma("unroll")                                                         \
      for (int kk_ = 0; kk_ < KK; ++kk_) {                                      \
        int cc_ = (kk_ * 4 + lh) ^ (row_ & SWM);                                \
        af[fi_][kk_] = *(const vec8*)(Ab_ + row_ * RB + cc_ * 16);              \
      }                                                                         \
    }                                                                           \
  }
#define LDB_ALL(buf)                                                            \
  {                                                                             \
    char* Bb_ = smem + (buf)*BUFSZ + ABUF;                                      \
    _Pragma("unroll")                                                           \
    for (int n_ = 0; n_ < NFR; ++n_) {                                          \
      int row_ = wn * (BN / 4) + n_ * 16 + lr;                                  \
      _Pragma("unroll")                                                         \
      for (int kk_ = 0; kk_ < KK; ++kk_) {                                      \
        int cc_ = (kk_ * 4 + lh) ^ (row_ & SWM);                                \
        bfr[n_][kk_] = *(const vec8*)(Bb_ + row_ * RB + cc_ * 16);              \
      }                                                                         \
    }                                                                           \
  }
#define MFMA_PHASE(p)                                                           \
  {                                                                             \
    _Pragma("unroll")                                                           \
    for (int fi_ = 0; fi_ < 2; ++fi_) {                                         \
      _Pragma("unroll")                                                         \
      for (int n_ = 0; n_ < NFR; ++n_) {                                        \
        _Pragma("unroll")                                                       \
        for (int kk_ = 0; kk_ < KK; ++kk_)                                      \
          acc[(p)*2 + fi_][n_] = mfma16(af[fi_][kk_], bfr[n_][kk_],             \
                                        acc[(p)*2 + fi_][n_]);                  \
      }                                                                         \
    }                                                                           \
  }
#define BAR() __builtin_amdgcn_s_barrier()
#define LGK0()                                          \
  asm volatile("s_waitcnt lgkmcnt(0)" ::: "memory");    \
  __builtin_amdgcn_sched_barrier(0)

  // prologue
  if constexpr (NFR == 4) {
    STAGE_B(0, 0, k0); STAGE_B(0, 1, k0); STAGE_A(0, 0, k0); STAGE_A(0, 1, k0);
  } else {
    STAGE_B(0, 0, k0); STAGE_A(0, 0, k0); STAGE_A(0, 1, k0);
  }
  vmcnt_wait<IPU>();  // last A-half still in flight
  BAR();

  for (int t = 0; t < NT; ++t) {
    const int cur = t & 1, nxt = cur ^ 1;
    const int ktn = k0 + (t + 1) * BK;
    const bool st = (t < NT - 1);
    // ---- ph0: uses B + A-half0 ----
    if (st) { STAGE_B(nxt, 0, ktn); }
    LDB_ALL(cur);
    LDA_PHASE(cur, 0);
    BAR(); LGK0();
    __builtin_amdgcn_s_setprio(1); MFMA_PHASE(0); __builtin_amdgcn_s_setprio(0);
    BAR();
    // ---- ph1: uses A-half0 ----
    if (st) {
      if constexpr (NFR == 4) { STAGE_B(nxt, 1, ktn); } else { STAGE_A(nxt, 0, ktn); }
    }
    LDA_PHASE(cur, 1);
    BAR(); LGK0();
    __builtin_amdgcn_s_setprio(1); MFMA_PHASE(1); __builtin_amdgcn_s_setprio(0);
    if (st) { vmcnt_wait<2 * IPU>(); }  // A-half1(t) landed
    else    { vmcnt_wait<0>(); }
    BAR();
    // ---- ph2: uses A-half1 ----
    if (st) {
      if constexpr (NFR == 4) { STAGE_A(nxt, 0, ktn); } else { STAGE_A(nxt, 1, ktn); }
    }
    LDA_PHASE(cur, 2);
    BAR(); LGK0();
    __builtin_amdgcn_s_setprio(1); MFMA_PHASE(2); __builtin_amdgcn_s_setprio(0);
    BAR();
    // ---- ph3: uses A-half1 ----
    if (st) {
      if constexpr (NFR == 4) { STAGE_A(nxt, 1, ktn); }
    }
    LDA_PHASE(cur, 3);
    BAR(); LGK0();
    __builtin_amdgcn_s_setprio(1); MFMA_PHASE(3); __builtin_amdgcn_s_setprio(0);
    if (st) { vmcnt_wait<IPU>(); }  // next tile's B(+A0) landed
    BAR();
  }

  // ---- epilogue ----
  const int row0 = blkM * 256;
  const int col0 = blkN * BN + wn * (BN / 4);
  const int ldc = args.ldc;
  if constexpr (EPI == 1) {
    // exp + store + per-(blkN,wn) rowsum partials (sum over this wave's cols)
#pragma unroll
    for (int a = 0; a < 8; ++a) {
      float rsv[4] = {0.f, 0.f, 0.f, 0.f};
#pragma unroll
      for (int n = 0; n < NFR; ++n) {
#pragma unroll
        for (int rr = 0; rr < 4; ++rr) {
          int row = row0 + (a * 2 + wm) * 16 + lh * 4 + rr;
          int col = col0 + n * 16 + lr;
          float e = __expf(acc[a][n][rr]);
          ((bf16*)args.C[z])[(size_t)row * ldc + col] = (bf16)e;
          rsv[rr] += e;
        }
      }
#pragma unroll
      for (int rr = 0; rr < 4; ++rr) {
        float s = rsv[rr];
        s += __shfl_xor(s, 1);
        s += __shfl_xor(s, 2);
        s += __shfl_xor(s, 4);
        s += __shfl_xor(s, 8);
        if (lr == 0) {
          int row = row0 + (a * 2 + wm) * 16 + lh * 4 + rr;
          args.rsO[z][((size_t)blkN * 4 + wn) * NROWS + row] = s;
        }
      }
    }
  } else {
#pragma unroll
    for (int a = 0; a < 8; ++a) {
#pragma unroll
      for (int n = 0; n < NFR; ++n) {
#pragma unroll
        for (int rr = 0; rr < 4; ++rr) {
          int row = row0 + (a * 2 + wm) * 16 + lh * 4 + rr;
          int col = col0 + n * 16 + lr;
          float v = acc[a][n][rr];
          if constexpr (EPI == 0) {
            float b = v + args.bias[z][col];
            if (args.storebf[z])
              ((bf16*)args.C[z])[(size_t)row * ldc + col] = (bf16)b;
            else
              ((f16*)args.C[z])[(size_t)row * ldc + col] = (f16)b;
          } else if constexpr (EPI == 2) {
            ((float*)args.C[z])[(size_t)row * ldc + col] = v;
          } else {
            ((float*)args.C[z])[(size_t)row * ldc + col] = v + args.bias[z][col];
          }
        }
      }
    }
  }
#undef STAGE_A
#undef STAGE_B
#undef LDA_PHASE
#undef LDB_ALL
#undef MFMA_PHASE
#undef BAR
#undef LGK0
}

// ---------------- launch ----------------

extern "C" void kernel_launch(void* const* d_in, const int* in_sizes, int n_in,
                              void* d_out, int out_size, void* d_ws, size_t ws_size,
                              hipStream_t stream) {
  const float* in1 = (const float*)d_in[0];
  const float* in2 = (const float*)d_in[1];
  const float* Wq = (const float*)d_in[2];
  const float* bq = (const float*)d_in[3];
  const float* Wk = (const float*)d_in[4];
  const float* bk = (const float*)d_in[5];
  const float* Wv = (const float*)d_in[6];
  const float* bv = (const float*)d_in[7];
  const float* Wo = (const float*)d_in[8];
  const float* bo = (const float*)d_in[9];
  float* out = (float*)d_out;

  const size_t IN_E = (size_t)NROWS * DIN;   // 4M
  const size_t WT_E = (size_t)DA * DIN;      // 512K
  const size_t QS = (size_t)NROWS * DA;      // 2M
  const size_t PS = (size_t)NROWS * NROWS;   // 16M

  f16* qk = (f16*)d_ws;                      // 16 MB (dead after QK)
  f16* in_hf = qk + 4 * QS;                  // 16 MB (dead after proj)
  bf16* vv = (bf16*)(in_hf + 2 * IN_E);      // 8 MB (dead after transpose)
  f16* wt = (f16*)(vv + 2 * QS);             // 3 MB
  f16* woT = wt + 3 * WT_E;                  // 1 MB
  bf16* vt = (bf16*)(woT + WT_E);            // 8 MB
  bf16* P = vt + 2 * QS;                     // 64 MB
  f16* mid = (f16*)(P + 2 * PS);             // 8 MB
  float* pO = (float*)d_ws;                  // 32 MB, aliases qk+in_hf (dead then)
  float* prsP = (float*)vv;                  // 2 MB rowsum partials, aliases vv
  float* prsT = prsP + 2 * 64 * NROWS;       // 32 KB totals

  // 1. cast inputs to fp16
  cast_kernel<<<dim3((unsigned)(IN_E / 1024), 1, 2), dim3(256), 0, stream>>>(
      in1, in2, in_hf, in_hf + IN_E, (int)IN_E);

  // 2. transpose-cast weights
  transpose_f32<<<dim3(DA / 32, DIN / 32, 3), dim3(32, 8), 0, stream>>>(
      Wq, Wk, Wv, wt, WT_E, DIN, DA);
  transpose_f32<<<dim3(DIN / 32, DA / 32, 1), dim3(32, 8), 0, stream>>>(
      Wo, Wo, Wo, woT, 0, DA, DIN);

  // 3. projections (8-phase 256x256, BK=64): z = Q1,K1,Q2,K2,V1,V2
  {
    G8Args<f16> a{};
    const float* bs[3] = {bq, bk, bv};
    for (int zi = 0; zi < 6; ++zi) {
      int which = (zi < 4) ? (zi & 1) : 2;
      int src = (zi < 4) ? (zi >> 1) : (zi - 4);
      a.A[zi] = in_hf + (size_t)src * IN_E;
      a.B[zi] = wt + (size_t)which * WT_E;
      a.bias[zi] = bs[which];
      a.C[zi] = (zi < 4) ? (void*)(qk + (size_t)zi * QS) : (void*)(vv + (size_t)(zi - 4) * QS);
      a.storebf[zi] = (zi >= 4);
      a.k0[zi] = 0;
    }
    a.lda = DIN; a.ldb = DIN; a.ldc = DA;
    g8<f16, 0, 256, 16, 64><<<dim3(2, 16, 6), dim3(512), 0, stream>>>(a);
  }

  // 4. V -> Vt ([4096,512] -> [512][4096])
  transpose_b16<<<dim3(DA / 32, NROWS / 32, 2), dim3(32, 8), 0, stream>>>(
      vv, QS, vt, QS, NROWS, DA);

  // 5. P = exp(Q @ K^T) + rowsum partials (8-phase 256x256, BK=32 -> 2 blk/CU)
  {
    G8Args<f16> a{};
    a.A[0] = qk + 0 * QS; a.B[0] = qk + 3 * QS; a.C[0] = P;
    a.A[1] = qk + 2 * QS; a.B[1] = qk + 1 * QS; a.C[1] = P + PS;
    a.rsO[0] = prsP;
    a.rsO[1] = prsP + (size_t)64 * NROWS;
    a.k0[0] = a.k0[1] = 0;
    a.lda = DA; a.ldb = DA; a.ldc = NROWS;
    g8<f16, 1, 256, 16, 32, 2><<<dim3(16, 16, 2), dim3(512), 0, stream>>>(a);
  }

  // 5b. reduce rowsum partials
  rowsum_reduce<<<dim3(32), dim3(256), 0, stream>>>(prsP, prsT);

  // 6. PV split-K partials (8-phase 256x128, BK=64): z = split*2 + pair
  {
    G8Args<bf16> a{};
    for (int i = 0; i < 4; ++i) {
      int pair = i & 1, s = i >> 1;
      a.A[i] = P + (size_t)pair * PS;
      a.B[i] = vt + (size_t)(pair ^ 1) * QS;
      a.C[i] = pO + (size_t)i * QS;
      a.k0[i] = s * 2048;
      a.storebf[i] = 0;
    }
    a.lda = NROWS; a.ldb = NROWS; a.ldc = DA;
    g8<bf16, 2, 128, 32, 64><<<dim3(4, 16, 4), dim3(512), 0, stream>>>(a);
  }

  // 7. merge partials -> mid (f16)
  merge_kernel<<<dim3((unsigned)(2 * QS / 1024)), dim3(256), 0, stream>>>(pO, prsT, mid);

  // 8. out = mid @ Wo + bo (8-phase 256x128 g8, f32+bias)
  {
    G8Args<f16> a{};
    a.A[0] = mid;      a.C[0] = out;
    a.A[1] = mid + QS; a.C[1] = out + (size_t)NROWS * DIN;
    a.B[0] = a.B[1] = woT;
    a.bias[0] = a.bias[1] = bo;
    a.k0[0] = a.k0[1] = 0;
    a.lda = DA; a.ldb = DA; a.ldc = DIN;
    g8<f16, 3, 128, 8, 64><<<dim3(8, 16, 2), dim3(512), 0, stream>>>(a);
  }
}